// Round 9
// baseline (342.896 us; speedup 1.0000x reference)
//
#include <hip/hip_runtime.h>

// BMM_S8T_S8N_F16T: out[b,m,n] = fp16-range(alpha * sum_k A[b,m,k]*B[b,n,k])
// A: (B,M,K) int32 (int8-range), B: (B,N,K) int32, out: float. B=64, M=N=1024, K=128.
//
// R12 PROBE: true kernel ~97us; harness fixed overhead ~233us. WRITE=268MB
//   exact, FETCH=33MB (no amplification anywhere). Occupancy 23% (8 waves),
//   MfmaUtil 2%, VALUBusy 19% -> ISSUE-SIDE bound, not traffic bound.
// R13 (-7.6us, kernel ~90us): zero in-loop barriers, wave-private transpose.
// R11 retrospective: 2 blk/CU REGRESSED, but it still had 128 block-wide
//   barriers shared by 16 waves (the exact thing R12 indicted). Its per-CU
//   stage traffic equaled R9's. The untested cell: 2 blk/CU + barrier-free.
// R14 = R13 epilogue x R11 split: block (z, q m-quarter, h n-half) = 256m x
//   512n. Bs 64KB (512 B-rows) + 8KB wave bufs = 72KB LDS -> 2 blocks/CU,
//   16 free-running wave streams: block A's serial stage + fence bubbles
//   hide under block B's MFMA/stores. Stores: 1KB contiguous per instr
//   (4 rows x 256B, whole lines). Epilogue write-swizzle nt^rl: 2-way (free).

#define Mdim 1024
#define Ndim 1024
#define Kdim 128
#define NROWS 16     // m-rows per strip
#define NSTRIPS 16   // strips per block -> 256 m-rows
#define HROWS 512    // B rows (n) staged per block = n-half
#define BSTRIDE 128  // packed bytes per B row (no pad; XOR swizzle)
#define WAVEBUF 1024 // per-wave transpose buffer (4 rows x 256 B)

using int32x4 = __attribute__((ext_vector_type(4))) int;
using floatx4 = __attribute__((ext_vector_type(4))) float;

__device__ __forceinline__ unsigned pack8(int32x4 v) {
    return (unsigned)(v.x & 255) | ((unsigned)(v.y & 255) << 8)
         | ((unsigned)(v.z & 255) << 16) | ((unsigned)(v.w & 255) << 24);
}

// B-tile swizzle: XOR row&7 into the 16-B-unit bits (bijective per row).
__device__ __forceinline__ int swz(int byte_off) {
    return byte_off ^ (((byte_off >> 7) & 7) << 4);
}

// Same-wave LDS drain (no barrier, no vmcnt): orders ds_write -> ds_read
// within the wave; sched_barrier stops hoisting across it (guide rule #18).
__device__ __forceinline__ void wave_lds_fence() {
    asm volatile("s_waitcnt lgkmcnt(0)" ::: "memory");
    __builtin_amdgcn_sched_barrier(0);
}

__global__ __launch_bounds__(512, 4)
void bmm_s8_kernel(const int* __restrict__ A, const int* __restrict__ Bm,
                   const float* __restrict__ alpha_p, float* __restrict__ out)
{
    __shared__ unsigned char Bs[HROWS * BSTRIDE];  // 64 KiB: half-B, packed int8
    __shared__ unsigned char Ws[8 * WAVEBUF];      // 8 KiB: wave-private bufs

    const int t    = threadIdx.x;
    const int z    = blockIdx.x;   // batch; linear%8 == z%8 -> per-XCD batch affinity
    const int q    = blockIdx.y;   // m-quarter: rows [q*256, q*256+256)
    const int h    = blockIdx.z;   // n-half: cols [h*512, h*512+512)
    const int lane = t & 63;
    const int wave = t >> 6;       // 0..7
    const int wn   = wave * 64;    // wave's n band within the half

    const int* __restrict__ Ab = A  + (size_t)z * Mdim * Kdim + (size_t)(q * 256) * Kdim;
    const int* __restrict__ Bb = Bm + (size_t)z * Ndim * Kdim + (size_t)(h * HROWS) * Kdim;
    float* __restrict__ Ob     = out + (size_t)z * Mdim * Ndim + (size_t)(q * 256) * Ndim
                                     + (size_t)(h * HROWS);

    const int r = lane & 15;   // fragment m-row within 16
    const int g = lane >> 4;   // fragment k-chunk selector / 4-col group

    // ---- issue A prefetch for strip 0 (oldest loads; land during staging) ----
    int32x4 araw[8];
#pragma unroll
    for (int k = 0; k < 8; ++k) {
        const int ks = k >> 2, i = k & 3;
        araw[k] = *(const int32x4*)(Ab + (size_t)r * Kdim + ks * 64 + g * 16 + i * 4);
    }

    // ---- stage half-B (512 rows x 32 16-B chunks = 16384 chunks) ----
    // 512 threads x 32 chunks, 4 rounds of {8 loads, 8 packed stores}.
#pragma unroll 1
    for (int rr = 0; rr < 4; ++rr) {
        int32x4 breg[8];
#pragma unroll
        for (int j = 0; j < 8; ++j) {
            const int f    = t + 512 * (rr * 8 + j);
            const int row  = f >> 5;             // 0..511 across rounds
            const int colb = (f & 31) * 4;
            breg[j] = *(const int32x4*)(Bb + (size_t)row * Kdim + colb);
        }
#pragma unroll
        for (int j = 0; j < 8; ++j) {
            const int f    = t + 512 * (rr * 8 + j);
            const int row  = f >> 5;
            const int colb = (f & 31) * 4;
            *(unsigned*)(&Bs[swz(row * BSTRIDE + colb)]) = pack8(breg[j]);
        }
    }
    __syncthreads();  // the ONLY block-wide barrier in the kernel

    const float alpha = alpha_p[0];
    unsigned char* const Wb = &Ws[wave * WAVEBUF];

#pragma unroll 1
    for (int s = 0; s < NSTRIPS; ++s) {
        // consume prefetched A into fragments
        int32x4 af[2];
#pragma unroll
        for (int ks = 0; ks < 2; ++ks)
            af[ks] = (int32x4){ (int)pack8(araw[ks * 4 + 0]), (int)pack8(araw[ks * 4 + 1]),
                                (int)pack8(araw[ks * 4 + 2]), (int)pack8(araw[ks * 4 + 3]) };

        // issue next strip's A loads (in flight across compute + stores)
        if (s + 1 < NSTRIPS) {
            const int* __restrict__ An = Ab + (size_t)((s + 1) * NROWS) * Kdim;
#pragma unroll
            for (int k = 0; k < 8; ++k) {
                const int ks = k >> 2, i = k & 3;
                araw[k] = *(const int32x4*)(An + (size_t)r * Kdim + ks * 64 + g * 16 + i * 4);
            }
        }

        // ---- MFMA: wave computes 16(m) x 64(n) of this strip ----
        int32x4 acc[4];
#pragma unroll
        for (int nt = 0; nt < 4; ++nt)
            acc[nt] = (int32x4){0, 0, 0, 0};

#pragma unroll
        for (int ks = 0; ks < 2; ++ks) {
#pragma unroll
            for (int nt = 0; nt < 4; ++nt) {
                const int row = wn + nt * 16 + r;
                int32x4 bf = *(const int32x4*)(&Bs[swz(row * BSTRIDE + ks * 64 + g * 16)]);
                // swapped operands: D cols = m (lane&15), regs = 4 consecutive n
                acc[nt] = __builtin_amdgcn_mfma_i32_16x16x64_i8(bf, af[ks], acc[nt], 0, 0, 0);
            }
        }

        // convert: lane holds out[m = r][n = wn + nt*16 + g*4 + 0..3]
        floatx4 facc[4];
#pragma unroll
        for (int nt = 0; nt < 4; ++nt) {
            facc[nt].x = alpha * (float)acc[nt][0];
            facc[nt].y = alpha * (float)acc[nt][1];
            facc[nt].z = alpha * (float)acc[nt][2];
            facc[nt].w = alpha * (float)acc[nt][3];
        }

        // ---- epilogue: wave-private transpose, ZERO barriers.
        //      4 sub-chunks of 4 m-rows x 64 n (1 KB each). Write swizzle:
        //      unit = (nt^rl)*4+g -> 2-way bank alias (free). Read: lane l
        //      fetches (rowL=l>>4, u=l&15) at inverse swizzle; one 1-KB
        //      fully-contiguous nt-store per sub-chunk (4 rows x 256 B). ----
#pragma unroll
        for (int c = 0; c < 4; ++c) {
            wave_lds_fence();  // prior sub-chunk's reads done before overwrite
            if ((r >> 2) == c) {
                const int rl = r & 3;
#pragma unroll
                for (int nt = 0; nt < 4; ++nt)
                    *(floatx4*)(&Wb[rl * 256 + ((nt ^ rl) & 3) * 64 + g * 16]) = facc[nt];
            }
            wave_lds_fence();  // writes visible within the wave
            {
                const int rowL = lane >> 4;            // 0..3
                const int u    = lane & 15;            // 16-B unit within 256-B row
                floatx4 v = *(const floatx4*)(
                    &Wb[rowL * 256 + (((u >> 2) ^ rowL) & 3) * 64 + (u & 3) * 16]);
                const size_t fidx = (size_t)(s * NROWS + c * 4 + rowL) * Ndim
                                  + wn + u * 4;
                __builtin_nontemporal_store(v, (floatx4*)(Ob + fidx));
            }
        }
    }
}

extern "C" void kernel_launch(void* const* d_in, const int* in_sizes, int n_in,
                              void* d_out, int out_size, void* d_ws, size_t ws_size,
                              hipStream_t stream) {
    const int*   a     = (const int*)d_in[0];
    const int*   b     = (const int*)d_in[1];
    const float* alpha = (const float*)d_in[2];
    float*       out   = (float*)d_out;

    const int batch = in_sizes[0] / (Mdim * Kdim);  // 64
    dim3 grid(batch, Mdim / (NROWS * NSTRIPS), Ndim / HROWS);  // (64,4,2): 2 blocks/CU
    bmm_s8_kernel<<<grid, 512, 0, stream>>>(a, b, alpha, out);
}

// Round 10
// 334.575 us; speedup vs baseline: 1.0249x; 1.0249x over previous
//
#include <hip/hip_runtime.h>

// BMM_S8T_S8N_F16T: out[b,m,n] = fp16-range(alpha * sum_k A[b,m,k]*B[b,n,k])
// A: (B,M,K) int32 (int8-range), B: (B,N,K) int32, out: float. B=64, M=N=1024, K=128.
//
// R12 PROBE: true kernel ~97us; harness fixed overhead ~233us. WRITE=268MB
//   exact, FETCH=33MB (no amplification). Issue-side bound, not traffic.
// R13 (323.0, kernel ~90us): zero in-loop barriers, wave-private transpose. BEST.
// R11/R14: 2 blocks/CU regressed ~20us BOTH with and without barriers ->
//   occupancy direction closed; 1 block/CU + free-running waves wins.
// R15: two residual suspects attacked on the R13 base:
//   (a) wave-private B staging: each wave stages its OWN 128-row band into
//       its slice of Bs (same-wave lgkmcnt fence). ZERO barriers anywhere;
//       no wave ever waits on another wave's stage.
//   (b) NORMAL stores (nt removed; never isolated -- bundled into R9). B is
//       LDS-resident after stage, so L2 write-allocate can't thrash anything
//       that matters; L2 write-combining may beat the nt bypass path (fill
//       hits 6.3 TB/s with normal stores).

#define Mdim 1024
#define Ndim 1024
#define Kdim 128
#define NROWS 16     // m-rows per strip
#define NSTRIPS 16   // strips per block -> 256 m-rows
#define BSTRIDE 128  // packed bytes per B row (no pad; XOR swizzle instead)
#define WAVEBUF 2048 // per-wave transpose buffer (4 rows x 512 B)

using int32x4 = __attribute__((ext_vector_type(4))) int;
using floatx4 = __attribute__((ext_vector_type(4))) float;

__device__ __forceinline__ unsigned pack8(int32x4 v) {
    return (unsigned)(v.x & 255) | ((unsigned)(v.y & 255) << 8)
         | ((unsigned)(v.z & 255) << 16) | ((unsigned)(v.w & 255) << 24);
}

// B-tile swizzle: XOR row&7 into the 16-B-unit bits (bijective per row).
__device__ __forceinline__ int swz(int byte_off) {
    return byte_off ^ (((byte_off >> 7) & 7) << 4);
}

// Same-wave LDS drain (no barrier, no vmcnt): orders ds_write -> ds_read
// within the wave; sched_barrier stops hoisting across it (guide rule #18).
__device__ __forceinline__ void wave_lds_fence() {
    asm volatile("s_waitcnt lgkmcnt(0)" ::: "memory");
    __builtin_amdgcn_sched_barrier(0);
}

__global__ __launch_bounds__(512, 2)
void bmm_s8_kernel(const int* __restrict__ A, const int* __restrict__ Bm,
                   const float* __restrict__ alpha_p, float* __restrict__ out)
{
    __shared__ unsigned char Bs[1024 * BSTRIDE];  // 128 KiB: full B, packed int8
    __shared__ unsigned char Ws[8 * WAVEBUF];     // 16 KiB: wave-private transpose bufs

    const int t    = threadIdx.x;
    const int z    = blockIdx.x;   // batch; linear%8 == z%8 -> per-XCD batch affinity
    const int q    = blockIdx.y;   // m-quarter: rows [q*256, q*256+256)
    const int lane = t & 63;
    const int wave = t >> 6;       // 0..7
    const int wn   = wave * 128;   // this wave's n band

    const int* __restrict__ Ab = A  + (size_t)z * Mdim * Kdim + (size_t)(q * 256) * Kdim;
    const int* __restrict__ Bb = Bm + (size_t)z * Ndim * Kdim;
    float* __restrict__ Ob     = out + (size_t)z * Mdim * Ndim + (size_t)(q * 256) * Ndim;

    const int r = lane & 15;   // fragment m-row within 16
    const int g = lane >> 4;   // fragment k-chunk selector / 4-col group

    // ---- issue A prefetch for strip 0 (oldest loads; land during staging) ----
    int32x4 araw[8];
#pragma unroll
    for (int k = 0; k < 8; ++k) {
        const int ks = k >> 2, i = k & 3;
        araw[k] = *(const int32x4*)(Ab + (size_t)r * Kdim + ks * 64 + g * 16 + i * 4);
    }

    // ---- WAVE-PRIVATE stage: wave w stages its own 128-row band.
    //      128 rows x 32 chunks = 4096 chunks / 64 lanes = 64 chunks/lane,
    //      4 rounds of {16 loads, 16 packed LDS writes}. No cross-wave dep. ----
#pragma unroll 1
    for (int rr = 0; rr < 4; ++rr) {
        int32x4 breg[16];
#pragma unroll
        for (int j = 0; j < 16; ++j) {
            const int f    = lane + 64 * (rr * 16 + j);
            const int row  = wn + (f >> 5);      // own band rows wn..wn+127
            const int colb = (f & 31) * 4;
            breg[j] = *(const int32x4*)(Bb + (size_t)row * Kdim + colb);
        }
#pragma unroll
        for (int j = 0; j < 16; ++j) {
            const int f    = lane + 64 * (rr * 16 + j);
            const int row  = wn + (f >> 5);
            const int colb = (f & 31) * 4;
            *(unsigned*)(&Bs[swz(row * BSTRIDE + colb)]) = pack8(breg[j]);
        }
    }
    wave_lds_fence();  // own-band writes complete; NO block barrier anywhere

    const float alpha = alpha_p[0];
    unsigned char* const Wb = &Ws[wave * WAVEBUF];

#pragma unroll 1
    for (int s = 0; s < NSTRIPS; ++s) {
        // consume prefetched A into fragments
        int32x4 af[2];
#pragma unroll
        for (int ks = 0; ks < 2; ++ks)
            af[ks] = (int32x4){ (int)pack8(araw[ks * 4 + 0]), (int)pack8(araw[ks * 4 + 1]),
                                (int)pack8(araw[ks * 4 + 2]), (int)pack8(araw[ks * 4 + 3]) };

        // issue next strip's A loads (in flight across compute + stores)
        if (s + 1 < NSTRIPS) {
            const int* __restrict__ An = Ab + (size_t)((s + 1) * NROWS) * Kdim;
#pragma unroll
            for (int k = 0; k < 8; ++k) {
                const int ks = k >> 2, i = k & 3;
                araw[k] = *(const int32x4*)(An + (size_t)r * Kdim + ks * 64 + g * 16 + i * 4);
            }
        }

        // ---- MFMA: wave computes 16(m) x 128(n) of this strip ----
        int32x4 acc[8];
#pragma unroll
        for (int nt = 0; nt < 8; ++nt)
            acc[nt] = (int32x4){0, 0, 0, 0};

#pragma unroll
        for (int ks = 0; ks < 2; ++ks) {
#pragma unroll
            for (int nt = 0; nt < 8; ++nt) {
                const int row = wn + nt * 16 + r;     // own band only
                int32x4 bf = *(const int32x4*)(&Bs[swz(row * BSTRIDE + ks * 64 + g * 16)]);
                // swapped operands: D cols = m (lane&15), regs = 4 consecutive n
                acc[nt] = __builtin_amdgcn_mfma_i32_16x16x64_i8(bf, af[ks], acc[nt], 0, 0, 0);
            }
        }

        // convert once: lane holds out[m = r][n = wn + nt*16 + g*4 + 0..3]
        floatx4 facc[8];
#pragma unroll
        for (int nt = 0; nt < 8; ++nt) {
            facc[nt].x = alpha * (float)acc[nt][0];
            facc[nt].y = alpha * (float)acc[nt][1];
            facc[nt].z = alpha * (float)acc[nt][2];
            facc[nt].w = alpha * (float)acc[nt][3];
        }

        // ---- epilogue: wave-private transpose, zero barriers.
        //      4 sub-chunks of 4 m-rows x 128 n (2 KB each); same-wave lgkm
        //      fences; two 2-row x 512-B full-line store instructions. ----
#pragma unroll
        for (int c = 0; c < 4; ++c) {
            wave_lds_fence();  // prior sub-chunk's reads done before overwrite
            if ((r >> 2) == c) {
                const int rl = r & 3;
#pragma unroll
                for (int nt = 0; nt < 8; ++nt) {
                    const int inrow = nt * 64 + g * 16;       // byte off within 512-B row
                    *(floatx4*)(&Wb[rl * 512 + (inrow ^ (rl << 4))]) = facc[nt];
                }
            }
            wave_lds_fence();  // writes visible to all lanes of this wave
#pragma unroll
            for (int p = 0; p < 2; ++p) {
                const int rowL  = p * 2 + (lane >> 5);        // 0..3
                const int inrow = (lane & 31) * 16;
                floatx4 v = *(const floatx4*)(&Wb[rowL * 512 + (inrow ^ (rowL << 4))]);
                const size_t fidx = (size_t)(s * NROWS + c * 4 + rowL) * Ndim
                                  + wn + (lane & 31) * 4;
                *(floatx4*)(Ob + fidx) = v;                   // NORMAL store (nt removed)
            }
        }
    }
}

extern "C" void kernel_launch(void* const* d_in, const int* in_sizes, int n_in,
                              void* d_out, int out_size, void* d_ws, size_t ws_size,
                              hipStream_t stream) {
    const int*   a     = (const int*)d_in[0];
    const int*   b     = (const int*)d_in[1];
    const float* alpha = (const float*)d_in[2];
    float*       out   = (float*)d_out;

    const int batch = in_sizes[0] / (Mdim * Kdim);  // 64
    dim3 grid(batch, Mdim / (NROWS * NSTRIPS));     // (64, 4): 256 blocks = 1/CU
    bmm_s8_kernel<<<grid, 512, 0, stream>>>(a, b, alpha, out);
}

// Round 11
// 325.335 us; speedup vs baseline: 1.0540x; 1.0284x over previous
//
#include <hip/hip_runtime.h>

// BMM_S8T_S8N_F16T: out[b,m,n] = fp16-range(alpha * sum_k A[b,m,k]*B[b,n,k])
// A: (B,M,K) int32 (int8-range), B: (B,N,K) int32, out: float. B=64, M=N=1024, K=128.
//
// Ledger: stores (mode/geometry/macro-pattern), barriers, occupancy all
//   exonerated (R5-R15). R12 counters: WRITE=268MB exact, FETCH=33MB, kernel
//   ~93-97us vs ~45us floor, VALUBusy 19%, MfmaUtil 3% -> LATENCY-bound.
//   Per-strip LDS arithmetic: 448 instrs/CU (~5.4K cyc) dominated by the
//   masked 16/64-lane epilogue transpose (4x instr inflation) + 8 lgkm
//   round-trips per wave-strip, on only 2 waves/SIMD. R11/R14 regression
//   consistent: smaller per-wave work = worse chain-overhead ratio.
// R16: B FRAGMENTS IN REGISTERS (64 VGPR = own 128-row band, loaded once
//   via packed LDS stage + 16 conflict-free ds_read_b128). Inner loop: 16
//   MFMAs fully register-resident, ZERO LDS reads. Epilogue: all-64-lane
//   one-phase transpose (8 unmasked ds_w + 1 fence + 8 ds_r + 8 nt stores;
//   XOR swizzle, 8-pass conflict-free both sides) into the DEAD B-band LDS
//   (time-shared). Per wave-strip: LDS 56->16 instrs, fences 8->2. No
//   barriers anywhere. LDS 128KB, 1 block/CU (known-good regime).

#define Mdim 1024
#define Ndim 1024
#define Kdim 128
#define NROWS 16     // m-rows per strip
#define NSTRIPS 16   // strips per block -> 256 m-rows
#define BANDB 16384  // per-wave LDS band: 128 rows x 128 B packed

using int32x4 = __attribute__((ext_vector_type(4))) int;
using floatx4 = __attribute__((ext_vector_type(4))) float;

__device__ __forceinline__ unsigned pack8(int32x4 v) {
    return (unsigned)(v.x & 255) | ((unsigned)(v.y & 255) << 8)
         | ((unsigned)(v.z & 255) << 16) | ((unsigned)(v.w & 255) << 24);
}

// Band swizzle: XOR row&7 into the 16-B-unit index (bijective per row).
__device__ __forceinline__ int swz(int byte_off) {
    return byte_off ^ (((byte_off >> 7) & 7) << 4);
}

// Same-wave LDS drain; sched_barrier stops hoisting across it (rule #18).
__device__ __forceinline__ void wave_lds_fence() {
    asm volatile("s_waitcnt lgkmcnt(0)" ::: "memory");
    __builtin_amdgcn_sched_barrier(0);
}

__global__ __launch_bounds__(512, 2)
void bmm_s8_kernel(const int* __restrict__ A, const int* __restrict__ Bm,
                   const float* __restrict__ alpha_p, float* __restrict__ out)
{
    __shared__ unsigned char Bs[8 * BANDB];  // 128 KiB: 8 wave-private bands

    const int t    = threadIdx.x;
    const int z    = blockIdx.x;   // batch; linear%8 == z%8 -> per-XCD batch affinity
    const int q    = blockIdx.y;   // m-quarter: rows [q*256, q*256+256)
    const int lane = t & 63;
    const int wave = t >> 6;       // 0..7
    const int wn   = wave * 128;   // this wave's n band

    const int* __restrict__ Ab = A  + (size_t)z * Mdim * Kdim + (size_t)(q * 256) * Kdim;
    const int* __restrict__ Bb = Bm + (size_t)z * Ndim * Kdim;
    float* __restrict__ Ob     = out + (size_t)z * Mdim * Ndim + (size_t)(q * 256) * Ndim;

    const int r = lane & 15;   // fragment m-row within 16
    const int g = lane >> 4;   // fragment k-chunk selector / 4-col group

    unsigned char* const band = &Bs[wave * BANDB];

    // ---- issue A prefetch for strip 0 (oldest loads; land during staging) ----
    int32x4 araw[8];
#pragma unroll
    for (int k = 0; k < 8; ++k) {
        const int ks = k >> 2, i = k & 3;
        araw[k] = *(const int32x4*)(Ab + (size_t)r * Kdim + ks * 64 + g * 16 + i * 4);
    }

    // ---- stage OWN 128-row B band packed+swizzled (coalesced loads) ----
#pragma unroll 1
    for (int rr = 0; rr < 4; ++rr) {
        int32x4 breg[16];
#pragma unroll
        for (int j = 0; j < 16; ++j) {
            const int f    = lane + 64 * (rr * 16 + j);
            const int row  = f >> 5;             // 0..127 local band row
            const int colb = (f & 31) * 4;
            breg[j] = *(const int32x4*)(Bb + (size_t)(wn + row) * Kdim + colb);
        }
#pragma unroll
        for (int j = 0; j < 16; ++j) {
            const int f    = lane + 64 * (rr * 16 + j);
            const int row  = f >> 5;
            const int colb = (f & 31) * 4;
            *(unsigned*)(&band[swz(row * 128 + colb)]) = pack8(breg[j]);
        }
    }
    wave_lds_fence();

    // ---- load ALL 16 B fragments into registers (one-time; conflict-free).
    //      frag (nt,ks): lane (g,r) holds B[wn+nt*16+r][k = ks*64+g*16 ..+15].
    //      After this, the band LDS is DEAD -> reused as transpose buffer. ----
    int32x4 bfrag[8][2];
#pragma unroll
    for (int nt = 0; nt < 8; ++nt)
#pragma unroll
        for (int ks = 0; ks < 2; ++ks)
            bfrag[nt][ks] = *(const int32x4*)(
                &band[(nt * 16 + r) * 128 + (((ks * 4 + g) ^ (r & 7)) << 4)]);

    const float alpha = alpha_p[0];

#pragma unroll 1
    for (int s = 0; s < NSTRIPS; ++s) {
        // consume prefetched A into fragments
        int32x4 af[2];
#pragma unroll
        for (int ks = 0; ks < 2; ++ks)
            af[ks] = (int32x4){ (int)pack8(araw[ks * 4 + 0]), (int)pack8(araw[ks * 4 + 1]),
                                (int)pack8(araw[ks * 4 + 2]), (int)pack8(araw[ks * 4 + 3]) };

        // issue next strip's A loads (in flight across compute + stores)
        if (s + 1 < NSTRIPS) {
            const int* __restrict__ An = Ab + (size_t)((s + 1) * NROWS) * Kdim;
#pragma unroll
            for (int k = 0; k < 8; ++k) {
                const int ks = k >> 2, i = k & 3;
                araw[k] = *(const int32x4*)(An + (size_t)r * Kdim + ks * 64 + g * 16 + i * 4);
            }
        }

        // ---- MFMA: 16 back-to-back, ALL operands register-resident ----
        int32x4 acc[8];
#pragma unroll
        for (int nt = 0; nt < 8; ++nt)
            acc[nt] = (int32x4){0, 0, 0, 0};

#pragma unroll
        for (int ks = 0; ks < 2; ++ks)
#pragma unroll
            for (int nt = 0; nt < 8; ++nt)
                // swapped operands: D cols = m (lane&15), regs = 4 consecutive n
                acc[nt] = __builtin_amdgcn_mfma_i32_16x16x64_i8(
                    bfrag[nt][ks], af[ks], acc[nt], 0, 0, 0);

        // convert: lane holds out[m = r][n = wn + nt*16 + g*4 + 0..3]
        floatx4 facc[8];
#pragma unroll
        for (int nt = 0; nt < 8; ++nt) {
            facc[nt].x = alpha * (float)acc[nt][0];
            facc[nt].y = alpha * (float)acc[nt][1];
            facc[nt].z = alpha * (float)acc[nt][2];
            facc[nt].w = alpha * (float)acc[nt][3];
        }

        // ---- epilogue: ONE all-lane transpose phase (16 rows x 512 B = 8 KB
        //      in the dead band LDS). Write: lane (g,r), unit (nt*4+g)^(r&7)
        //      -> 8-pass conflict-free. Read: lane l, rows p*2+(l>>5), unit
        //      (l&31)^(row&7) -> conflict-free; two 512-B full-line rows per
        //      nt-store instruction. ----
        wave_lds_fence();  // (cheap: lgkm already 0 here except A-loads use lgkm? no—vm) safety vs prior reads
#pragma unroll
        for (int nt = 0; nt < 8; ++nt)
            *(floatx4*)(&band[r * 512 + (((nt * 4 + g) ^ (r & 7)) << 4)]) = facc[nt];
        wave_lds_fence();  // writes visible within the wave
#pragma unroll
        for (int p = 0; p < 8; ++p) {
            const int rw = p * 2 + (lane >> 5);   // 0..15
            const int u  = lane & 31;             // 16-B unit within 512-B row
            floatx4 v = *(const floatx4*)(&band[rw * 512 + ((u ^ (rw & 7)) << 4)]);
            const size_t fidx = (size_t)(s * NROWS + rw) * Ndim + wn + u * 4;
            __builtin_nontemporal_store(v, (floatx4*)(Ob + fidx));
        }
    }
}

extern "C" void kernel_launch(void* const* d_in, const int* in_sizes, int n_in,
                              void* d_out, int out_size, void* d_ws, size_t ws_size,
                              hipStream_t stream) {
    const int*   a     = (const int*)d_in[0];
    const int*   b     = (const int*)d_in[1];
    const float* alpha = (const float*)d_in[2];
    float*       out   = (float*)d_out;

    const int batch = in_sizes[0] / (Mdim * Kdim);  // 64
    dim3 grid(batch, Mdim / (NROWS * NSTRIPS));     // (64, 4): 256 blocks = 1/CU
    bmm_s8_kernel<<<grid, 512, 0, stream>>>(a, b, alpha, out);
}